// Round 8
// baseline (9864.503 us; speedup 1.0000x reference)
//
#include <hip/hip_runtime.h>
#include <hip/hip_bf16.h>
#include <cstdint>

// RateModel: h_{s+1} = tanh(W_rec h_s + b_rec + W_in x_s); out = W_out h + b_out
// B=32, Nt=2000 (sequential), N=512, N_in=128, N_out=64.
//
// k_scan R8: TIME-MULTIPLEXED groups. 16 WGs = 2 sets x 8 row-slices. Set s
// serves 4 chain-groups (4 chains each); per step each WG runs 4 phases, one
// per group. Polls for phase P are issued at phase P-2 (~1800cy earlier), so
// the data (published at P-4.. wait: published one step prior) is committed
// and the first poll HITS -> no retry quantization (R4 lost 2+ MALL RTTs/step
// to guaranteed-stale prefetches). Exchange protocol is bit-identical to R4's
// proven one: 8B atoms [payload32|tag32], permuted layout, sc0 sc1 (MALL,
// correct for ANY WG->XCD mapping), exact-match tags => no fences; stale
// exact-match data from an identical prior replay is bit-identical => benign;
// all-to-all consumption bounds skew to 1 step => 2 parity slots suffice.
// W_rec slice resident in registers (shared across the 4 groups - same rows).
// h = hi+lo bf16 -> 2 MFMA passes (~f32 precision). One barrier per phase;
// counted vmcnt(9) at phase top (exact: 9 vm-ops issue between a phase's
// polls and their consumption).

#define NB   32
#define NT   2000
#define NIN  128
#define NN   512
#define NOUT 64
#define NBNN (NB * NN)
#define PAR_OFF (8 * NBNN)   // byte offset between the two parity slots

typedef unsigned short u16;
typedef unsigned int   u32;
typedef unsigned long long u64;
typedef __bf16 bf16x8 __attribute__((ext_vector_type(8)));
typedef float  f32x4  __attribute__((ext_vector_type(4)));
typedef u32    u32x4  __attribute__((ext_vector_type(4)));

static __device__ __forceinline__ u16 f2bf(float f) {
  return __builtin_bit_cast(u16, (__bf16)f);   // RNE
}
static __device__ __forceinline__ float bf2f(u16 u) {
  return (float)__builtin_bit_cast(__bf16, u);
}
static __device__ __forceinline__ void split_hl(float f, u16& hi, u16& lo) {
  const u32 u = __float_as_uint(f);
  hi = (u16)(u >> 16);                                   // truncated bf16
  lo = f2bf(f - __uint_as_float(u & 0xffff0000u));       // residual
}
static __device__ __forceinline__ float fast_tanh(float x) {
  const float xc = fminf(fmaxf(x, -12.f), 12.f);
  const float t = __builtin_amdgcn_exp2f(xc * 2.8853900817779268f); // 2*log2(e)
  return (t - 1.f) * __builtin_amdgcn_rcpf(t + 1.f);
}

// device-scope (MALL) 16B ops; vmcnt-only, invisible to compiler's wait model
static __device__ __forceinline__ u32x4 ld_dev16(const void* p) {
  u32x4 r;
  asm volatile("global_load_dwordx4 %0, %1, off sc0 sc1" : "=v"(r) : "v"(p) : "memory");
  return r;
}
static __device__ __forceinline__ void st_dev16(void* p, u32x4 v) {
  asm volatile("global_store_dwordx4 %0, %1, off sc0 sc1" :: "v"(p), "v"(v) : "memory");
}
static __device__ __forceinline__ void ld_u16(u32& d, const void* p) {
  asm volatile("global_load_ushort %0, %1, off" : "=v"(d) : "v"(p) : "memory");
}

// ---------------- prep: bf16 weight tables --------------------------------
__global__ __launch_bounds__(256) void k_prep_in(const float* __restrict__ Win,
                                                 u16* __restrict__ winh) {
  const int e = blockIdx.x * 256 + threadIdx.x;
  if (e < NN * NIN) winh[e] = f2bf(Win[e]);
}
__global__ __launch_bounds__(256) void k_prep_out(const float* __restrict__ Wout,
                                                  u16* __restrict__ wouth) {
  const int e = blockIdx.x * 256 + threadIdx.x;
  if (e < NOUT * NN) wouth[e] = f2bf(Wout[e]);
}

// ---------------- K1 (MFMA): jx[t][b][n] = sum_k x[b][t][k] * Win[n][k] ----
__global__ __launch_bounds__(256) void k_in(const float* __restrict__ x,
                                            const u16* __restrict__ winh,
                                            u16* __restrict__ jx) {
  const int t = blockIdx.x;
  const int tid = threadIdx.x;
  const int wv = tid >> 6, lane = tid & 63;
  __shared__ u16 Xh[NB][136];
  __shared__ u16 Xl[NB][136];
  {
    const int b = tid >> 3, k0 = (tid & 7) * 16;
    const float* xp = x + ((size_t)b * NT + t) * NIN + k0;
    u16 hb[16], lb[16];
#pragma unroll
    for (int j = 0; j < 16; ++j) split_hl(xp[j], hb[j], lb[j]);
    *(uint4*)&Xh[b][k0]     = *(uint4*)&hb[0];
    *(uint4*)&Xh[b][k0 + 8] = *(uint4*)&hb[8];
    *(uint4*)&Xl[b][k0]     = *(uint4*)&lb[0];
    *(uint4*)&Xl[b][k0 + 8] = *(uint4*)&lb[8];
  }
  __syncthreads();

  const int r15 = lane & 15, kg = lane >> 4;
  const int n0 = 128 * wv;
  f32x4 acc[2][8];
#pragma unroll
  for (int mt = 0; mt < 2; ++mt)
#pragma unroll
    for (int nt = 0; nt < 8; ++nt) acc[mt][nt] = (f32x4){0.f, 0.f, 0.f, 0.f};

#pragma unroll
  for (int kt = 0; kt < 4; ++kt) {
    const int ko = 32 * kt + 8 * kg;
    const bf16x8 ah0 = *(const bf16x8*)&Xh[r15][ko];
    const bf16x8 ah1 = *(const bf16x8*)&Xh[16 + r15][ko];
    const bf16x8 al0 = *(const bf16x8*)&Xl[r15][ko];
    const bf16x8 al1 = *(const bf16x8*)&Xl[16 + r15][ko];
#pragma unroll
    for (int nt = 0; nt < 8; ++nt) {
      const int n = n0 + 16 * nt + r15;
      const bf16x8 bh = *(const bf16x8*)(winh + (size_t)n * NIN + ko);
      acc[0][nt] = __builtin_amdgcn_mfma_f32_16x16x32_bf16(ah0, bh, acc[0][nt], 0, 0, 0);
      acc[1][nt] = __builtin_amdgcn_mfma_f32_16x16x32_bf16(ah1, bh, acc[1][nt], 0, 0, 0);
      acc[0][nt] = __builtin_amdgcn_mfma_f32_16x16x32_bf16(al0, bh, acc[0][nt], 0, 0, 0);
      acc[1][nt] = __builtin_amdgcn_mfma_f32_16x16x32_bf16(al1, bh, acc[1][nt], 0, 0, 0);
    }
  }
#pragma unroll
  for (int mt = 0; mt < 2; ++mt)
#pragma unroll
    for (int nt = 0; nt < 8; ++nt) {
      const int n = n0 + 16 * nt + r15;
#pragma unroll
      for (int r = 0; r < 4; ++r) {
        const int b = 16 * mt + 4 * kg + r;
        jx[((size_t)t * NB + b) * NN + n] = f2bf(acc[mt][nt][r]);
      }
    }
}

// ---------------- K2: sequential scan, 4-group time-multiplex --------------
// One phase of one group. GP literal; C* = consume poll set (issued 2 phases
// ago); I* = issue poll set (for phase+2); TGTN = 0 (target same step) or 1
// (target next step). vmcnt(9): after this phase's polls were issued, exactly
// [1 jx + 3 stores + 4 polls + 1 jx] = 9 vm-ops precede their consumption.
#define PHASE(GP, C0, C1, C2, C3, I0, I1, I2, I3, TGTN)                          \
  do {                                                                           \
    const int slot_ = s & 1;                                                     \
    if (s > 0) {                                                                 \
      asm volatile("s_waitcnt vmcnt(9)" ::: "memory");                           \
      __builtin_amdgcn_sched_barrier(0);                                         \
      const u32 want_ = (u32)s;                                                  \
      bool ok_ = (C0.y == want_) & (C0.w == want_) & (C1.y == want_) &           \
                 (C1.w == want_) & (C2.y == want_) & (C2.w == want_) &           \
                 (C3.y == want_) & (C3.w == want_);                              \
      const char* cbs_ = cbp[GP] + (slot_ ? PAR_OFF : 0);                        \
      int tries_ = 1 << 16;                                                      \
      while (!__all(ok_) && --tries_) {                                          \
        C0 = ld_dev16(cbs_);                                                     \
        C1 = ld_dev16(cbs_ + 1024);                                              \
        C2 = ld_dev16(cbs_ + 2048);                                              \
        C3 = ld_dev16(cbs_ + 3072);                                              \
        asm volatile("s_waitcnt vmcnt(0)" ::: "memory");                         \
        __builtin_amdgcn_sched_barrier(0);                                       \
        ok_ = (C0.y == want_) & (C0.w == want_) & (C1.y == want_) &              \
              (C1.w == want_) & (C2.y == want_) & (C2.w == want_) &              \
              (C3.y == want_) & (C3.w == want_);                                 \
      }                                                                          \
      const u32x4 hw_ = {(C0.x >> 16) | (C0.z & 0xffff0000u),                    \
                         (C1.x >> 16) | (C1.z & 0xffff0000u),                    \
                         (C2.x >> 16) | (C2.z & 0xffff0000u),                    \
                         (C3.x >> 16) | (C3.z & 0xffff0000u)};                   \
      const u32x4 lw_ = {(C0.x & 0xffffu) | (C0.z << 16),                        \
                         (C1.x & 0xffffu) | (C1.z << 16),                        \
                         (C2.x & 0xffffu) | (C2.z << 16),                        \
                         (C3.x & 0xffffu) | (C3.z << 16)};                       \
      *(u32x4*)&SHhi[GP][slot_][sc][8 * t64] = hw_;                              \
      *(u32x4*)&SHlo[GP][slot_][sc][8 * t64] = lw_;                              \
    }                                                                            \
    Pj[GP][slot_][sc][t64] = __uint_as_float(jxu[GP] << 16) + brv;               \
    asm volatile("s_waitcnt lgkmcnt(0)" ::: "memory");                           \
    __builtin_amdgcn_s_barrier();                                                \
    __builtin_amdgcn_sched_barrier(0);                                           \
    f32x4 ah0_ = {0.f, 0.f, 0.f, 0.f}, ah1_ = {0.f, 0.f, 0.f, 0.f};              \
    f32x4 al0_ = {0.f, 0.f, 0.f, 0.f}, al1_ = {0.f, 0.f, 0.f, 0.f};              \
    if (s > 0) {                                                                 \
      const int c4_ = cc & 3;                                                    \
      _Pragma("unroll")                                                          \
      for (int kt = 0; kt < 8; ++kt) {                                           \
        const int ko_ = 32 * kt + 8 * kg, ko2_ = 32 * (kt + 8) + 8 * kg;         \
        const bf16x8 bh0_ = *(const bf16x8*)&SHhi[GP][slot_][c4_][ko_];          \
        const bf16x8 bh1_ = *(const bf16x8*)&SHhi[GP][slot_][c4_][ko2_];         \
        const bf16x8 bl0_ = *(const bf16x8*)&SHlo[GP][slot_][c4_][ko_];          \
        const bf16x8 bl1_ = *(const bf16x8*)&SHlo[GP][slot_][c4_][ko2_];         \
        ah0_ = __builtin_amdgcn_mfma_f32_16x16x32_bf16(afrag[kt], bh0_, ah0_, 0, 0, 0); \
        ah1_ = __builtin_amdgcn_mfma_f32_16x16x32_bf16(afrag[kt + 8], bh1_, ah1_, 0, 0, 0); \
        al0_ = __builtin_amdgcn_mfma_f32_16x16x32_bf16(afrag[kt], bl0_, al0_, 0, 0, 0); \
        al1_ = __builtin_amdgcn_mfma_f32_16x16x32_bf16(afrag[kt + 8], bl1_, al1_, 0, 0, 0); \
      }                                                                          \
    }                                                                            \
    const f32x4 acc_ = (ah0_ + ah1_) + (al0_ + al1_);                            \
    if (cc < 4) {                                                                \
      u32 pl_[4];                                                                \
      u16 hp_[4];                                                                \
      _Pragma("unroll")                                                          \
      for (int r = 0; r < 4; ++r) {                                              \
        const float pre_ = acc_[r] + Pj[GP][slot_][cc][rb + r];                  \
        const float h_ = fast_tanh(pre_);                                        \
        const u32 uh_ = __float_as_uint(h_);                                     \
        const u16 lo_ = f2bf(h_ - __uint_as_float(uh_ & 0xffff0000u));           \
        pl_[r] = (uh_ & 0xffff0000u) | (u32)lo_;                                 \
        hp_[r] = (u16)(uh_ >> 16);                                               \
      }                                                                          \
      const u32 tg_ = (u32)(s + 1);                                              \
      char* pbs_ = pbp[GP] + (((s + 1) & 1) ? PAR_OFF : 0);                      \
      st_dev16(pbs_,        (u32x4){pl_[0], tg_, pl_[1], tg_});                  \
      st_dev16(pbs_ + 1024, (u32x4){pl_[2], tg_, pl_[3], tg_});                  \
      uint2 hv_;                                                                 \
      hv_.x = (u32)hp_[0] | ((u32)hp_[1] << 16);                                 \
      hv_.y = (u32)hp_[2] | ((u32)hp_[3] << 16);                                 \
      *(uint2*)hbp[GP] = hv_;                                                    \
    }                                                                            \
    hbp[GP] += NBNN;                                                             \
    {                                                                            \
      const int ts_ = s + TGTN;                                                  \
      const char* cbn_ = cbp[(GP + 2) & 3] + ((ts_ & 1) ? PAR_OFF : 0);          \
      I0 = ld_dev16(cbn_);                                                       \
      I1 = ld_dev16(cbn_ + 1024);                                                \
      I2 = ld_dev16(cbn_ + 2048);                                                \
      I3 = ld_dev16(cbn_ + 3072);                                                \
    }                                                                            \
    ld_u16(jxu[GP], jpp[GP]);                                                    \
    jpp[GP] += 2 * NBNN;                                                         \
  } while (0)

__global__ __launch_bounds__(256) void k_scan(const float* __restrict__ Wrec,
                                              const float* __restrict__ brec,
                                              const u16* __restrict__ jx,
                                              u64* Hex,             // [2][NB][NN] atoms (permuted)
                                              u16* __restrict__ Hh) // [NT][NB][NN]
{
  const int wg = blockIdx.x;          // 16 WGs
  const int sigma = wg >> 3;          // set: groups 4*sigma .. 4*sigma+3
  const int i = wg & 7;               // row-slice (rows 64i..64i+63)
  const int tid = threadIdx.x;
  const int wv = tid >> 6, lane = tid & 63;

  // [group][slot][chain][k]; stride 528 u16 = 264 dw == 8 (mod 32) -> 2-way = free
  __shared__ u16 SHhi[4][2][4][528];
  __shared__ u16 SHlo[4][2][4][528];
  __shared__ float Pj[4][2][4][64];

  const int r15 = lane & 15, kg = lane >> 4;
  const int t64 = tid & 63;
  const float brv = brec[64 * i + t64];

  // resident A-frags (shared by all 4 groups): row = lane&15, k = 8*kg + j
  const int arow = 64 * i + 16 * wv + r15;
  bf16x8 afrag[16];
#pragma unroll
  for (int kt = 0; kt < 16; ++kt) {
    const float* wp = Wrec + (size_t)arow * NN + 32 * kt + 8 * kg;
    bf16x8 a;
#pragma unroll
    for (int j = 0; j < 8; ++j) a[j] = (__bf16)wp[j];
    afrag[kt] = a;
  }

  const int sc = wv;                 // staged chain (== wave)
  const int cc = r15;                // D col = chain (valid < 4)
  const int rb = 16 * wv + 4 * kg;   // D row base within WG slice
  const size_t ro = (size_t)(64 * i + rb);
  const int e0 = (rb & 4) >> 1;

  char* HexB = (char*)Hex;
  char* cbp[4];
  char* pbp[4];
  const char* jpp[4];
  u16* hbp[4];
  u32 jxu[4];
#pragma unroll
  for (int gp = 0; gp < 4; ++gp) {
    const int g = 4 * sigma + gp;
    cbp[gp] = HexB + 8 * ((size_t)(4 * g + sc) * NN) + 16 * t64;
    pbp[gp] = HexB + 8 * ((size_t)(4 * g + (cc & 3)) * NN) + (ro >> 3) * 16 + (size_t)e0 * 1024;
    jpp[gp] = (const char*)jx + ((size_t)(NB + 4 * g + sc) * NN + 64 * i + t64) * 2;
    hbp[gp] = Hh + (size_t)(4 * g + (cc & 3)) * NN + ro;
    ld_u16(jxu[gp], (const char*)jx + ((size_t)(4 * g + sc) * NN + 64 * i + t64) * 2);
  }
  asm volatile("s_waitcnt vmcnt(0)" ::: "memory");
  __builtin_amdgcn_sched_barrier(0);

  // poll register sets: pair (phase0<->phase2): U,V; pair (phase1<->phase3): X,Y
  u32x4 U0{}, U1{}, U2{}, U3{}, V0{}, V1{}, V2{}, V3{};
  u32x4 X0{}, X1{}, X2{}, X3{}, Y0{}, Y1{}, Y2{}, Y3{};

  for (int s = 0; s < NT; ++s) {
    PHASE(0, U0, U1, U2, U3, V0, V1, V2, V3, 0);  // consume U (from prev gp2), issue V -> gp2
    PHASE(1, X0, X1, X2, X3, Y0, Y1, Y2, Y3, 0);  // consume X (from prev gp3), issue Y -> gp3
    PHASE(2, V0, V1, V2, V3, U0, U1, U2, U3, 1);  // consume V, issue U -> next-step gp0
    PHASE(3, Y0, Y1, Y2, Y3, X0, X1, X2, X3, 1);  // consume Y, issue X -> next-step gp1
  }
}

// ---------------- K3 (MFMA): out[b][t][o] = sum_n Hh[t][b][n]*Wout[o][n] + bout[o]
__global__ __launch_bounds__(256) void k_out(const u16* __restrict__ Hh,
                                             const u16* __restrict__ wouth,
                                             const float* __restrict__ bout,
                                             float* __restrict__ out) {
  const int t = blockIdx.x;
  const int tid = threadIdx.x;
  const int wv = tid >> 6, lane = tid & 63;
  __shared__ u16 Ah[NB][528];
  {
    const int b = tid >> 3, k0 = (tid & 7) * 64;
    const u16* hp = Hh + ((size_t)t * NB + b) * NN + k0;
#pragma unroll
    for (int j = 0; j < 8; ++j)
      *(uint4*)&Ah[b][k0 + 8 * j] = *(const uint4*)(hp + 8 * j);
  }
  __syncthreads();

  const int r15 = lane & 15, kg = lane >> 4;
  const int o = 16 * wv + r15;
  f32x4 acc[2] = {{0.f, 0.f, 0.f, 0.f}, {0.f, 0.f, 0.f, 0.f}};
#pragma unroll
  for (int kt = 0; kt < 16; ++kt) {
    const int ko = 32 * kt + 8 * kg;
    const bf16x8 b0 = *(const bf16x8*)(wouth + (size_t)o * NN + ko);
    const bf16x8 a0 = *(const bf16x8*)&Ah[r15][ko];
    const bf16x8 a1 = *(const bf16x8*)&Ah[16 + r15][ko];
    acc[0] = __builtin_amdgcn_mfma_f32_16x16x32_bf16(a0, b0, acc[0], 0, 0, 0);
    acc[1] = __builtin_amdgcn_mfma_f32_16x16x32_bf16(a1, b0, acc[1], 0, 0, 0);
  }
  const float bo = bout[o];
#pragma unroll
  for (int mt = 0; mt < 2; ++mt)
#pragma unroll
    for (int r = 0; r < 4; ++r) {
      const int b = 16 * mt + 4 * kg + r;
      out[((size_t)b * NT + t) * NOUT + o] = acc[mt][r] + bo;
    }
}

// ---------------- launch ----------------------------------------------------
// ws: [0, 65,536,000)             jx bf16 [NT][NB][NN]  (post-scan: wouth @ +0)
//     [65,536,000, 131,072,000)   Hh bf16 [NT][NB][NN]  (pre-scan: winh @ +0)
//     [131,072,000, 131,334,144)  Hex u64 [2][NB][NN]   (permuted atom layout)
extern "C" void kernel_launch(void* const* d_in, const int* in_sizes, int n_in,
                              void* d_out, int out_size, void* d_ws, size_t ws_size,
                              hipStream_t stream) {
  (void)in_sizes; (void)n_in; (void)out_size;
  const float* x    = (const float*)d_in[0];
  const float* Wrec = (const float*)d_in[1];
  const float* brec = (const float*)d_in[2];
  const float* Win  = (const float*)d_in[3];
  const float* Wout = (const float*)d_in[4];
  const float* bout = (const float*)d_in[5];
  float* out = (float*)d_out;

  if (ws_size < 131334144ULL) return;  // visible failure beacon

  char* ws = (char*)d_ws;
  u16* jx    = (u16*)ws;
  u16* Hh    = (u16*)(ws + 65536000);
  u64* Hex   = (u64*)(ws + 131072000);
  u16* winh  = (u16*)(ws + 65536000);  // overlays Hh (dead until k_scan)
  u16* wouth = (u16*)ws;               // overlays jx (dead after k_scan)

  k_prep_in<<<dim3((NN * NIN + 255) / 256), dim3(256), 0, stream>>>(Win, winh);
  k_in<<<dim3(NT), dim3(256), 0, stream>>>(x, winh, jx);
  k_scan<<<dim3(16), dim3(256), 0, stream>>>(Wrec, brec, jx, Hex, Hh);
  k_prep_out<<<dim3((NOUT * NN + 255) / 256), dim3(256), 0, stream>>>(Wout, wouth);
  k_out<<<dim3(NT), dim3(256), 0, stream>>>(Hh, wouth, bout, out);
}

// Round 9
// 5798.454 us; speedup vs baseline: 1.7012x; 1.7012x over previous
//
#include <hip/hip_runtime.h>
#include <hip/hip_bf16.h>
#include <cstdint>

// RateModel: h_{s+1} = tanh(W_rec h_s + b_rec + W_in x_s); out = W_out h + b_out
// B=32, Nt=2000 (sequential), N=512, N_in=128, N_out=64.
//
// k_scan R9: PAIRWISE exchange. 16 WGs x 1024 threads (16 waves): 8 groups
// (4 chains each) x 2 row-slices (256 rows). Each WG has exactly ONE exchange
// peer; own 256 rows are self-staged via LDS (never polled) -> own MALL commit
// off the critical path. Per-thread poll = ONE 8B atom. Protocol bit-identical
// to R4's proven one: 8B atoms [payload32|tag32] ([hi16|lo16] payload),
// permuted layout, sc0 sc1 (device/MALL -> correct for ANY WG placement),
// exact-match tags => no fences; stale exact-match data from an identical
// prior replay is bit-identical => benign; pairwise tag-wait bounds skew to 1
// step => 2 parity slots suffice. Epilogue vm order: poll -> jx -> Hh ->
// stores; step-top waits vmcnt(3) so own store acks never gate the tag check.
// h = hi+lo bf16 -> 2 MFMA passes; W_rec slice resident in registers.

#define NB   32
#define NT   2000
#define NIN  128
#define NN   512
#define NOUT 64
#define NBNN (NB * NN)
#define PAR_OFF (8 * NBNN)   // bytes between the two parity slots of Hex

typedef unsigned short u16;
typedef unsigned int   u32;
typedef unsigned long long u64;
typedef __bf16 bf16x8 __attribute__((ext_vector_type(8)));
typedef float  f32x4  __attribute__((ext_vector_type(4)));
typedef u32    u32x4  __attribute__((ext_vector_type(4)));

static __device__ __forceinline__ u16 f2bf(float f) {
  return __builtin_bit_cast(u16, (__bf16)f);   // RNE
}
static __device__ __forceinline__ float bf2f(u16 u) {
  return (float)__builtin_bit_cast(__bf16, u);
}
static __device__ __forceinline__ void split_hl(float f, u16& hi, u16& lo) {
  const u32 u = __float_as_uint(f);
  hi = (u16)(u >> 16);                                   // truncated bf16
  lo = f2bf(f - __uint_as_float(u & 0xffff0000u));       // residual
}
static __device__ __forceinline__ float fast_tanh(float x) {
  const float xc = fminf(fmaxf(x, -12.f), 12.f);
  const float t = __builtin_amdgcn_exp2f(xc * 2.8853900817779268f); // 2*log2(e)
  return (t - 1.f) * __builtin_amdgcn_rcpf(t + 1.f);
}

// device-scope (MALL) ops; vmcnt-only, invisible to compiler's wait model
static __device__ __forceinline__ u64 ld_dev8(const void* p) {
  u64 r;
  asm volatile("global_load_dwordx2 %0, %1, off sc0 sc1" : "=v"(r) : "v"(p) : "memory");
  return r;
}
static __device__ __forceinline__ void st_dev16(void* p, u32x4 v) {
  asm volatile("global_store_dwordx4 %0, %1, off sc0 sc1" :: "v"(p), "v"(v) : "memory");
}
static __device__ __forceinline__ void st_plain8(void* p, u64 v) {
  asm volatile("global_store_dwordx2 %0, %1, off" :: "v"(p), "v"(v) : "memory");
}
static __device__ __forceinline__ void ld_u16a(u32& d, const void* p) {
  asm volatile("global_load_ushort %0, %1, off" : "=v"(d) : "v"(p) : "memory");
}

// ---------------- prep: bf16 weight tables --------------------------------
__global__ __launch_bounds__(256) void k_prep_in(const float* __restrict__ Win,
                                                 u16* __restrict__ winh) {
  const int e = blockIdx.x * 256 + threadIdx.x;
  if (e < NN * NIN) winh[e] = f2bf(Win[e]);
}
__global__ __launch_bounds__(256) void k_prep_out(const float* __restrict__ Wout,
                                                  u16* __restrict__ wouth) {
  const int e = blockIdx.x * 256 + threadIdx.x;
  if (e < NOUT * NN) wouth[e] = f2bf(Wout[e]);
}

// ---------------- K1 (MFMA): jx[t][b][n] = sum_k x[b][t][k] * Win[n][k] ----
__global__ __launch_bounds__(256) void k_in(const float* __restrict__ x,
                                            const u16* __restrict__ winh,
                                            u16* __restrict__ jx) {
  const int t = blockIdx.x;
  const int tid = threadIdx.x;
  const int wv = tid >> 6, lane = tid & 63;
  __shared__ u16 Xh[NB][136];
  __shared__ u16 Xl[NB][136];
  {
    const int b = tid >> 3, k0 = (tid & 7) * 16;
    const float* xp = x + ((size_t)b * NT + t) * NIN + k0;
    u16 hb[16], lb[16];
#pragma unroll
    for (int j = 0; j < 16; ++j) split_hl(xp[j], hb[j], lb[j]);
    *(uint4*)&Xh[b][k0]     = *(uint4*)&hb[0];
    *(uint4*)&Xh[b][k0 + 8] = *(uint4*)&hb[8];
    *(uint4*)&Xl[b][k0]     = *(uint4*)&lb[0];
    *(uint4*)&Xl[b][k0 + 8] = *(uint4*)&lb[8];
  }
  __syncthreads();

  const int r15 = lane & 15, kg = lane >> 4;
  const int n0 = 128 * wv;
  f32x4 acc[2][8];
#pragma unroll
  for (int mt = 0; mt < 2; ++mt)
#pragma unroll
    for (int nt = 0; nt < 8; ++nt) acc[mt][nt] = (f32x4){0.f, 0.f, 0.f, 0.f};

#pragma unroll
  for (int kt = 0; kt < 4; ++kt) {
    const int ko = 32 * kt + 8 * kg;
    const bf16x8 ah0 = *(const bf16x8*)&Xh[r15][ko];
    const bf16x8 ah1 = *(const bf16x8*)&Xh[16 + r15][ko];
    const bf16x8 al0 = *(const bf16x8*)&Xl[r15][ko];
    const bf16x8 al1 = *(const bf16x8*)&Xl[16 + r15][ko];
#pragma unroll
    for (int nt = 0; nt < 8; ++nt) {
      const int n = n0 + 16 * nt + r15;
      const bf16x8 bh = *(const bf16x8*)(winh + (size_t)n * NIN + ko);
      acc[0][nt] = __builtin_amdgcn_mfma_f32_16x16x32_bf16(ah0, bh, acc[0][nt], 0, 0, 0);
      acc[1][nt] = __builtin_amdgcn_mfma_f32_16x16x32_bf16(ah1, bh, acc[1][nt], 0, 0, 0);
      acc[0][nt] = __builtin_amdgcn_mfma_f32_16x16x32_bf16(al0, bh, acc[0][nt], 0, 0, 0);
      acc[1][nt] = __builtin_amdgcn_mfma_f32_16x16x32_bf16(al1, bh, acc[1][nt], 0, 0, 0);
    }
  }
#pragma unroll
  for (int mt = 0; mt < 2; ++mt)
#pragma unroll
    for (int nt = 0; nt < 8; ++nt) {
      const int n = n0 + 16 * nt + r15;
#pragma unroll
      for (int r = 0; r < 4; ++r) {
        const int b = 16 * mt + 4 * kg + r;
        jx[((size_t)t * NB + b) * NN + n] = f2bf(acc[mt][nt][r]);
      }
    }
}

// ---------------- K2: sequential scan, pairwise exchange -------------------
__global__ __launch_bounds__(1024, 1) void k_scan(const float* __restrict__ Wrec,
                                                  const float* __restrict__ brec,
                                                  const u16* __restrict__ jx,
                                                  u64* Hex,             // [2][NB][NN] atoms (permuted)
                                                  u16* __restrict__ Hh) // [NT][NB][NN]
{
  const int wg = blockIdx.x;          // 16 WGs
  const int g = wg & 7;               // chain group (chains 4g..4g+3)
  const int i = wg >> 3;              // row slice: rows [256i, 256i+256)
  const int tid = threadIdx.x;        // 0..1023
  const int wv = tid >> 6;            // 16 waves
  const int lane = tid & 63;
  const int r15 = lane & 15, kg = lane >> 4;

  // stride 528 u16 keeps B-frag ds_read_b128 near-conflict-free (m136)
  __shared__ u16 SHhi[2][4][528];
  __shared__ u16 SHlo[2][4][528];
  __shared__ float Pj[2][4][256];

  // resident A-frags: wave wv owns rows [256i+16wv, +16); A row = lane&15
  const int arow = 256 * i + 16 * wv + r15;
  bf16x8 afrag[16];
#pragma unroll
  for (int kt = 0; kt < 16; ++kt) {
    const float* wp = Wrec + (size_t)arow * NN + 32 * kt + 8 * kg;
    bf16x8 a;
#pragma unroll
    for (int j = 0; j < 8; ++j) a[j] = (__bf16)wp[j];
    afrag[kt] = a;
  }

  const int sc = wv & 3;              // consumer/staging chain
  const int q  = wv >> 2;             // k-quarter within peer range
  const int rr = 64 * q + lane;       // own-row index 0..255 (Pj staging)
  const float brv = brec[256 * i + rr];

  const int cc = r15;                 // D col = chain (valid < 4)
  const int rb = 16 * wv + 4 * kg;    // D row base within WG slice (0..255)
  const int gch = 4 * g + cc;
  const int ro = 256 * i + rb;        // global row of D rows ro..ro+3
  const int kown = ro;                // self-stage k index

  char* HexB = (char*)Hex;
  // consumer: ONE peer element k = 256*(i^1) + 64*q + lane
  const int kpe = 256 * (i ^ 1) + 64 * q + lane;
  const char* cb = HexB + 8 * ((size_t)(4 * g + sc) * NN)
                 + (size_t)((kpe & 7) >> 1) * 1024 + (kpe >> 3) * 16 + (kpe & 1) * 8;
  // producer: atoms (ro..ro+3) -> two 16B lines at e0, e0+1
  const int e0 = (ro & 4) >> 1;
  char* pb = HexB + 8 * ((size_t)gch * NN) + (ro >> 3) * 16 + (size_t)e0 * 1024;

  const char* jp = (const char*)jx + ((size_t)(NB + 4 * g + sc) * NN + 256 * i + rr) * 2;
  u16* hb = Hh + (size_t)gch * NN + ro;

  const float jxv0 = bf2f(jx[(size_t)(4 * g + sc) * NN + 256 * i + rr]);
  u32 jxu = 0;
  u64 pq = 0;

  for (int s = 0; s < NT; ++s) {
    const int slot = s & 1;
    if (s > 0) {
      // poll+jx prefetched last step; vmcnt(3) leaves Hh + 2 store acks pending
      asm volatile("s_waitcnt vmcnt(3)" ::: "memory");
      __builtin_amdgcn_sched_barrier(0);
      const u32 want = (u32)s;
      bool ok = ((u32)(pq >> 32) == want);
      const char* cbs = cb + (slot ? PAR_OFF : 0);
      int tries = (s == 1) ? (1 << 20) : (1 << 16);   // anti-hang guard only
      while (!__all(ok) && --tries) {
        pq = ld_dev8(cbs);
        asm volatile("s_waitcnt vmcnt(0)" ::: "memory");
        __builtin_amdgcn_sched_barrier(0);
        ok = ((u32)(pq >> 32) == want);
      }
      // stage peer element; payload = [hi16|lo16]
      const u32 pp = (u32)pq;
      SHhi[slot][sc][kpe] = (u16)(pp >> 16);
      SHlo[slot][sc][kpe] = (u16)pp;
      Pj[slot][sc][rr] = __uint_as_float(jxu << 16) + brv;
    } else {
      Pj[0][sc][rr] = jxv0 + brv;
    }

    // single barrier per step: drains only LDS writes (globals are vmcnt-only)
    asm volatile("s_waitcnt lgkmcnt(0)" ::: "memory");
    __builtin_amdgcn_s_barrier();
    __builtin_amdgcn_sched_barrier(0);

    // 4 independent MFMA chains: hi/lo x K-halves
    f32x4 ah0 = {0.f, 0.f, 0.f, 0.f}, ah1 = {0.f, 0.f, 0.f, 0.f};
    f32x4 al0 = {0.f, 0.f, 0.f, 0.f}, al1 = {0.f, 0.f, 0.f, 0.f};
    if (s > 0) {
      const int c4 = cc & 3;
#pragma unroll
      for (int kt = 0; kt < 8; ++kt) {
        const int ko  = 32 * kt + 8 * kg;
        const int ko2 = 32 * (kt + 8) + 8 * kg;
        const bf16x8 bh0 = *(const bf16x8*)&SHhi[slot][c4][ko];
        const bf16x8 bh1 = *(const bf16x8*)&SHhi[slot][c4][ko2];
        const bf16x8 bl0 = *(const bf16x8*)&SHlo[slot][c4][ko];
        const bf16x8 bl1 = *(const bf16x8*)&SHlo[slot][c4][ko2];
        ah0 = __builtin_amdgcn_mfma_f32_16x16x32_bf16(afrag[kt],     bh0, ah0, 0, 0, 0);
        ah1 = __builtin_amdgcn_mfma_f32_16x16x32_bf16(afrag[kt + 8], bh1, ah1, 0, 0, 0);
        al0 = __builtin_amdgcn_mfma_f32_16x16x32_bf16(afrag[kt],     bl0, al0, 0, 0, 0);
        al1 = __builtin_amdgcn_mfma_f32_16x16x32_bf16(afrag[kt + 8], bl1, al1, 0, 0, 0);
      }
    }
    const f32x4 acc = (ah0 + ah1) + (al0 + al1);

    // epilogue
    const int nsl = (s + 1) & 1;
    u32 pl[4];
    u64 hv = 0;
    if (cc < 4) {
      u16 hp[4], lp[4];
#pragma unroll
      for (int r = 0; r < 4; ++r) {
        const float pre = acc[r] + Pj[slot][cc][rb + r];
        const float h = fast_tanh(pre);
        const u32 uh = __float_as_uint(h);
        lp[r] = f2bf(h - __uint_as_float(uh & 0xffff0000u));
        hp[r] = (u16)(uh >> 16);
        pl[r] = (uh & 0xffff0000u) | (u32)lp[r];
      }
      // self-stage own rows into next-slot LDS (peer rows come via polls)
      uint2 hw2, lw2;
      hw2.x = (u32)hp[0] | ((u32)hp[1] << 16);
      hw2.y = (u32)hp[2] | ((u32)hp[3] << 16);
      lw2.x = (u32)lp[0] | ((u32)lp[1] << 16);
      lw2.y = (u32)lp[2] | ((u32)lp[3] << 16);
      *(uint2*)&SHhi[nsl][cc][kown] = hw2;
      *(uint2*)&SHlo[nsl][cc][kown] = lw2;
      hv = (u64)hw2.x | ((u64)hw2.y << 32);
    }
    // (1) poll prefetch + jx FIRST (never queued behind store acks)
    if (s + 1 < NT) {
      pq = ld_dev8(cb + (nsl ? PAR_OFF : 0));
      ld_u16a(jxu, jp);
      jp += 2 * NBNN;
    }
    // (2) history + publish to peer (fire-and-forget; acks drain off-path)
    if (cc < 4) {
      st_plain8(hb, hv);
      const u32 tg = (u32)(s + 1);
      char* pbs = pb + (nsl ? PAR_OFF : 0);
      st_dev16(pbs,        (u32x4){pl[0], tg, pl[1], tg});
      st_dev16(pbs + 1024, (u32x4){pl[2], tg, pl[3], tg});
    }
    hb += NBNN;
  }
}

// ---------------- K3 (MFMA): out[b][t][o] = sum_n Hh[t][b][n]*Wout[o][n] + bout[o]
__global__ __launch_bounds__(256) void k_out(const u16* __restrict__ Hh,
                                             const u16* __restrict__ wouth,
                                             const float* __restrict__ bout,
                                             float* __restrict__ out) {
  const int t = blockIdx.x;
  const int tid = threadIdx.x;
  const int wv = tid >> 6, lane = tid & 63;
  __shared__ u16 Ah[NB][528];
  {
    const int b = tid >> 3, k0 = (tid & 7) * 64;
    const u16* hp = Hh + ((size_t)t * NB + b) * NN + k0;
#pragma unroll
    for (int j = 0; j < 8; ++j)
      *(uint4*)&Ah[b][k0 + 8 * j] = *(const uint4*)(hp + 8 * j);
  }
  __syncthreads();

  const int r15 = lane & 15, kg = lane >> 4;
  const int o = 16 * wv + r15;
  f32x4 acc[2] = {{0.f, 0.f, 0.f, 0.f}, {0.f, 0.f, 0.f, 0.f}};
#pragma unroll
  for (int kt = 0; kt < 16; ++kt) {
    const int ko = 32 * kt + 8 * kg;
    const bf16x8 b0 = *(const bf16x8*)(wouth + (size_t)o * NN + ko);
    const bf16x8 a0 = *(const bf16x8*)&Ah[r15][ko];
    const bf16x8 a1 = *(const bf16x8*)&Ah[16 + r15][ko];
    acc[0] = __builtin_amdgcn_mfma_f32_16x16x32_bf16(a0, b0, acc[0], 0, 0, 0);
    acc[1] = __builtin_amdgcn_mfma_f32_16x16x32_bf16(a1, b0, acc[1], 0, 0, 0);
  }
  const float bo = bout[o];
#pragma unroll
  for (int mt = 0; mt < 2; ++mt)
#pragma unroll
    for (int r = 0; r < 4; ++r) {
      const int b = 16 * mt + 4 * kg + r;
      out[((size_t)b * NT + t) * NOUT + o] = acc[mt][r] + bo;
    }
}

// ---------------- launch ----------------------------------------------------
// ws: [0, 65,536,000)             jx bf16 [NT][NB][NN]  (post-scan: wouth @ +0)
//     [65,536,000, 131,072,000)   Hh bf16 [NT][NB][NN]  (pre-scan: winh @ +0)
//     [131,072,000, 131,334,144)  Hex u64 [2][NB][NN]   (permuted atom layout)
extern "C" void kernel_launch(void* const* d_in, const int* in_sizes, int n_in,
                              void* d_out, int out_size, void* d_ws, size_t ws_size,
                              hipStream_t stream) {
  (void)in_sizes; (void)n_in; (void)out_size;
  const float* x    = (const float*)d_in[0];
  const float* Wrec = (const float*)d_in[1];
  const float* brec = (const float*)d_in[2];
  const float* Win  = (const float*)d_in[3];
  const float* Wout = (const float*)d_in[4];
  const float* bout = (const float*)d_in[5];
  float* out = (float*)d_out;

  if (ws_size < 131334144ULL) return;  // visible failure beacon

  char* ws = (char*)d_ws;
  u16* jx    = (u16*)ws;
  u16* Hh    = (u16*)(ws + 65536000);
  u64* Hex   = (u64*)(ws + 131072000);
  u16* winh  = (u16*)(ws + 65536000);  // overlays Hh (dead until k_scan)
  u16* wouth = (u16*)ws;               // overlays jx (dead after k_scan)

  k_prep_in<<<dim3((NN * NIN + 255) / 256), dim3(256), 0, stream>>>(Win, winh);
  k_in<<<dim3(NT), dim3(256), 0, stream>>>(x, winh, jx);
  k_scan<<<dim3(16), dim3(1024), 0, stream>>>(Wrec, brec, jx, Hex, Hh);
  k_prep_out<<<dim3((NOUT * NN + 255) / 256), dim3(256), 0, stream>>>(Wout, wouth);
  k_out<<<dim3(NT), dim3(256), 0, stream>>>(Hh, wouth, bout, out);
}

// Round 11
// 3937.587 us; speedup vs baseline: 2.5052x; 1.4726x over previous
//
#include <hip/hip_runtime.h>
#include <hip/hip_bf16.h>
#include <cstdint>

// RateModel: h_{s+1} = tanh(W_rec h_s + b_rec + W_in x_s); out = W_out h + b_out
// B=32, Nt=2000 (sequential), N=512, N_in=128, N_out=64.
//
// k_scan R11 (R4 structure: 64 WGs = 8 groups x 8 row-slices, 256 thr):
//  - Exchange atom = 4B [hi16 | lo13 | tag3], tag = step&7, sc0 sc1 (MALL,
//    device scope -> correct for ANY WG placement). One 16B store publishes 4
//    self-validated rows. Skew<=1 (all-to-all tag wait) => stale resident tag
//    differs by 2 (mod 8) => never false-validates. Hex memsetAsync(0) each
//    launch (kills 0xAA poison / cross-launch aliases). Deterministic,
//    replay-safe (stale exact-match data from identical prior replay is
//    bit-identical).
//  - POLLS ARE STRICTLY RTT-SERIALIZED (issue -> vmcnt(0) -> check). R10
//    lesson: overlapped loads to one address MSHR-merge and return the same
//    stale snapshot forever (livelock). No poll prefetch across the step
//    boundary: first round is issued AT step top, so its request passes the
//    MALL ~RTT/2 later -- after peers' publishes commit -> first-round hit.
//  - 4 independent MFMA chains (hi/lo x K-halves); W_rec slice resident in
//    registers; one raw barrier/step (lgkmcnt-only drain); jx prefetched.

#define NB   32
#define NT   2000
#define NIN  128
#define NN   512
#define NOUT 64
#define NBNN (NB * NN)
#define PAR  65536            // bytes between the two parity slots of Hex (u32[32][512])

typedef unsigned short u16;
typedef unsigned int   u32;
typedef unsigned long long u64;
typedef __bf16 bf16x8 __attribute__((ext_vector_type(8)));
typedef float  f32x4  __attribute__((ext_vector_type(4)));
typedef u32    u32x4  __attribute__((ext_vector_type(4)));

static __device__ __forceinline__ u16 f2bf(float f) {
  return __builtin_bit_cast(u16, (__bf16)f);   // RNE
}
static __device__ __forceinline__ float bf2f(u16 u) {
  return (float)__builtin_bit_cast(__bf16, u);
}
static __device__ __forceinline__ void split_hl(float f, u16& hi, u16& lo) {
  const u32 u = __float_as_uint(f);
  hi = (u16)(u >> 16);                                   // truncated bf16
  lo = f2bf(f - __uint_as_float(u & 0xffff0000u));       // residual
}
static __device__ __forceinline__ float fast_tanh(float x) {
  const float xc = fminf(fmaxf(x, -12.f), 12.f);
  const float t = __builtin_amdgcn_exp2f(xc * 2.8853900817779268f); // 2*log2(e)
  return (t - 1.f) * __builtin_amdgcn_rcpf(t + 1.f);
}

// device-scope (MALL) 16B ops; vmcnt-only, invisible to compiler's wait model
static __device__ __forceinline__ u32x4 ld_dev16(const void* p) {
  u32x4 r;
  asm volatile("global_load_dwordx4 %0, %1, off sc0 sc1" : "=v"(r) : "v"(p) : "memory");
  return r;
}
static __device__ __forceinline__ void st_dev16(void* p, u32x4 v) {
  asm volatile("global_store_dwordx4 %0, %1, off sc0 sc1" :: "v"(p), "v"(v) : "memory");
}
static __device__ __forceinline__ void ld_u16a(u32& d, const void* p) {
  asm volatile("global_load_ushort %0, %1, off" : "=v"(d) : "v"(p) : "memory");
}
static __device__ __forceinline__ bool tags8(u32x4 a, u32x4 b, u32 want) {
  return ((a.x & 7u) == want) & ((a.y & 7u) == want) &
         ((a.z & 7u) == want) & ((a.w & 7u) == want) &
         ((b.x & 7u) == want) & ((b.y & 7u) == want) &
         ((b.z & 7u) == want) & ((b.w & 7u) == want);
}

// ---------------- prep: bf16 weight tables --------------------------------
__global__ __launch_bounds__(256) void k_prep_in(const float* __restrict__ Win,
                                                 u16* __restrict__ winh) {
  const int e = blockIdx.x * 256 + threadIdx.x;
  if (e < NN * NIN) winh[e] = f2bf(Win[e]);
}
__global__ __launch_bounds__(256) void k_prep_out(const float* __restrict__ Wout,
                                                  u16* __restrict__ wouth) {
  const int e = blockIdx.x * 256 + threadIdx.x;
  if (e < NOUT * NN) wouth[e] = f2bf(Wout[e]);
}

// ---------------- K1 (MFMA): jx[t][b][n] = sum_k x[b][t][k] * Win[n][k] ----
__global__ __launch_bounds__(256) void k_in(const float* __restrict__ x,
                                            const u16* __restrict__ winh,
                                            u16* __restrict__ jx) {
  const int t = blockIdx.x;
  const int tid = threadIdx.x;
  const int wv = tid >> 6, lane = tid & 63;
  __shared__ u16 Xh[NB][136];
  __shared__ u16 Xl[NB][136];
  {
    const int b = tid >> 3, k0 = (tid & 7) * 16;
    const float* xp = x + ((size_t)b * NT + t) * NIN + k0;
    u16 hb[16], lb[16];
#pragma unroll
    for (int j = 0; j < 16; ++j) split_hl(xp[j], hb[j], lb[j]);
    *(uint4*)&Xh[b][k0]     = *(uint4*)&hb[0];
    *(uint4*)&Xh[b][k0 + 8] = *(uint4*)&hb[8];
    *(uint4*)&Xl[b][k0]     = *(uint4*)&lb[0];
    *(uint4*)&Xl[b][k0 + 8] = *(uint4*)&lb[8];
  }
  __syncthreads();

  const int r15 = lane & 15, kg = lane >> 4;
  const int n0 = 128 * wv;
  f32x4 acc[2][8];
#pragma unroll
  for (int mt = 0; mt < 2; ++mt)
#pragma unroll
    for (int nt = 0; nt < 8; ++nt) acc[mt][nt] = (f32x4){0.f, 0.f, 0.f, 0.f};

#pragma unroll
  for (int kt = 0; kt < 4; ++kt) {
    const int ko = 32 * kt + 8 * kg;
    const bf16x8 ah0 = *(const bf16x8*)&Xh[r15][ko];
    const bf16x8 ah1 = *(const bf16x8*)&Xh[16 + r15][ko];
    const bf16x8 al0 = *(const bf16x8*)&Xl[r15][ko];
    const bf16x8 al1 = *(const bf16x8*)&Xl[16 + r15][ko];
#pragma unroll
    for (int nt = 0; nt < 8; ++nt) {
      const int n = n0 + 16 * nt + r15;
      const bf16x8 bh = *(const bf16x8*)(winh + (size_t)n * NIN + ko);
      acc[0][nt] = __builtin_amdgcn_mfma_f32_16x16x32_bf16(ah0, bh, acc[0][nt], 0, 0, 0);
      acc[1][nt] = __builtin_amdgcn_mfma_f32_16x16x32_bf16(ah1, bh, acc[1][nt], 0, 0, 0);
      acc[0][nt] = __builtin_amdgcn_mfma_f32_16x16x32_bf16(al0, bh, acc[0][nt], 0, 0, 0);
      acc[1][nt] = __builtin_amdgcn_mfma_f32_16x16x32_bf16(al1, bh, acc[1][nt], 0, 0, 0);
    }
  }
#pragma unroll
  for (int mt = 0; mt < 2; ++mt)
#pragma unroll
    for (int nt = 0; nt < 8; ++nt) {
      const int n = n0 + 16 * nt + r15;
#pragma unroll
      for (int r = 0; r < 4; ++r) {
        const int b = 16 * mt + 4 * kg + r;
        jx[((size_t)t * NB + b) * NN + n] = f2bf(acc[mt][nt][r]);
      }
    }
}

// ---------------- K2: sequential scan --------------------------------------
__global__ __launch_bounds__(256) void k_scan(const float* __restrict__ Wrec,
                                              const float* __restrict__ brec,
                                              const u16* __restrict__ jx,
                                              u32* Hex,             // [2][NB][NN] 4B atoms
                                              u16* __restrict__ Hh) // [NT][NB][NN]
{
  const int wg = blockIdx.x;
  const int g = wg & 7, i = wg >> 3;
  const int tid = threadIdx.x;
  const int wv = tid >> 6, lane = tid & 63;

  // stride 528 u16 = 264 dw == 8 (mod 32): B-frag ds_read_b128 2-way -> free (m136)
  __shared__ u16 SHhi[2][4][528];
  __shared__ u16 SHlo[2][4][528];
  __shared__ float Pj[2][4][64];

  const int r15 = lane & 15, kg = lane >> 4;
  const int t64 = tid & 63;
  const float brv = brec[64 * i + t64];

  // resident A-frags: row = lane&15, k = 8*kg + j (contig-8)
  const int arow = 64 * i + 16 * wv + r15;
  bf16x8 afrag[16];
#pragma unroll
  for (int kt = 0; kt < 16; ++kt) {
    const float* wp = Wrec + (size_t)arow * NN + 32 * kt + 8 * kg;
    bf16x8 a;
#pragma unroll
    for (int j = 0; j < 8; ++j) a[j] = (__bf16)wp[j];
    afrag[kt] = a;
  }

  const int sc = wv;                 // staged chain (== wave)
  const int cc = r15;                // D col = chain (valid < 4)
  const int rb = 16 * wv + 4 * kg;   // D row base within WG slice
  const int gch = 4 * g + cc;
  const int ro = 64 * i + rb;        // global rows ro..ro+3 (ro%4==0)

  char* HexB = (char*)Hex;
  // consumer: rows 8*t64..+7 of chain sc -> 32B contiguous
  const char* cb = HexB + ((size_t)(4 * g + sc) * NN + 8 * t64) * 4;
  // producer: rows ro..ro+3 of chain gch -> one 16B line
  char* pb = HexB + ((size_t)gch * NN + ro) * 4;

  const char* jp = (const char*)jx + ((size_t)(NB + 4 * g + sc) * NN + 64 * i + t64) * 2;
  u16* hb = Hh + (size_t)gch * NN + ro;

  const float jxv0 = bf2f(jx[(size_t)(4 * g + sc) * NN + 64 * i + t64]);
  u32 jxu = 0;

  for (int s = 0; s < NT; ++s) {
    const int slot = s & 1;
    if (s > 0) {
      // FRESH poll at step top; strictly RTT-serialized rounds (no overlap:
      // overlapped same-address loads MSHR-merge to the same stale snapshot)
      const char* cbs = cb + (slot ? PAR : 0);
      const u32 want = (u32)s & 7u;
      u32x4 A0 = ld_dev16(cbs);
      u32x4 A1 = ld_dev16(cbs + 16);
      asm volatile("s_waitcnt vmcnt(0)" ::: "memory");  // also drains jx + acks
      __builtin_amdgcn_sched_barrier(0);
      bool ok = tags8(A0, A1, want);
      int guard = 1 << 16;                               // anti-hang only
      while (!__all(ok) && --guard) {
        A0 = ld_dev16(cbs);
        A1 = ld_dev16(cbs + 16);
        asm volatile("s_waitcnt vmcnt(0)" ::: "memory");
        __builtin_amdgcn_sched_barrier(0);
        ok = tags8(A0, A1, want);
      }
      // unpack: atom = [hi16 | lo13 | tag3]; rows ascend A0.x..A1.w
      const u32x4 hw = {(A0.x >> 16) | (A0.y & 0xffff0000u),
                        (A0.z >> 16) | (A0.w & 0xffff0000u),
                        (A1.x >> 16) | (A1.y & 0xffff0000u),
                        (A1.z >> 16) | (A1.w & 0xffff0000u)};
      const u32x4 lw = {(A0.x & 0xfff8u) | ((A0.y & 0xfff8u) << 16),
                        (A0.z & 0xfff8u) | ((A0.w & 0xfff8u) << 16),
                        (A1.x & 0xfff8u) | ((A1.y & 0xfff8u) << 16),
                        (A1.z & 0xfff8u) | ((A1.w & 0xfff8u) << 16)};
      *(u32x4*)&SHhi[slot][sc][8 * t64] = hw;
      *(u32x4*)&SHlo[slot][sc][8 * t64] = lw;
      Pj[slot][sc][t64] = __uint_as_float(jxu << 16) + brv;
    } else {
      Pj[0][sc][t64] = jxv0 + brv;
    }

    // single barrier per step: drains only LDS writes (globals are vmcnt-only)
    asm volatile("s_waitcnt lgkmcnt(0)" ::: "memory");
    __builtin_amdgcn_s_barrier();
    __builtin_amdgcn_sched_barrier(0);

    // 4 independent MFMA chains: hi/lo x K-halves (breaks dependent latency)
    f32x4 ah0 = {0.f, 0.f, 0.f, 0.f}, ah1 = {0.f, 0.f, 0.f, 0.f};
    f32x4 al0 = {0.f, 0.f, 0.f, 0.f}, al1 = {0.f, 0.f, 0.f, 0.f};
    if (s > 0) {
      const int c4 = cc & 3;
#pragma unroll
      for (int kt = 0; kt < 8; ++kt) {
        const int ko  = 32 * kt + 8 * kg;
        const int ko2 = 32 * (kt + 8) + 8 * kg;
        const bf16x8 bh0 = *(const bf16x8*)&SHhi[slot][c4][ko];
        const bf16x8 bh1 = *(const bf16x8*)&SHhi[slot][c4][ko2];
        const bf16x8 bl0 = *(const bf16x8*)&SHlo[slot][c4][ko];
        const bf16x8 bl1 = *(const bf16x8*)&SHlo[slot][c4][ko2];
        ah0 = __builtin_amdgcn_mfma_f32_16x16x32_bf16(afrag[kt],     bh0, ah0, 0, 0, 0);
        ah1 = __builtin_amdgcn_mfma_f32_16x16x32_bf16(afrag[kt + 8], bh1, ah1, 0, 0, 0);
        al0 = __builtin_amdgcn_mfma_f32_16x16x32_bf16(afrag[kt],     bl0, al0, 0, 0, 0);
        al1 = __builtin_amdgcn_mfma_f32_16x16x32_bf16(afrag[kt + 8], bl1, al1, 0, 0, 0);
      }
    }
    const f32x4 acc = (ah0 + ah1) + (al0 + al1);

    // epilogue: publish FIRST (earliest visibility), then Hh, then jx prefetch
    const int nsl = (s + 1) & 1;
    if (cc < 4) {
      const u32 tg = (u32)(s + 1) & 7u;
      u32 atom[4];
      u16 hp[4];
#pragma unroll
      for (int r = 0; r < 4; ++r) {
        const float pre = acc[r] + Pj[slot][cc][rb + r];
        const float h = fast_tanh(pre);
        const u32 uh = __float_as_uint(h);
        const u16 lo = f2bf(h - __uint_as_float(uh & 0xffff0000u));
        atom[r] = (uh & 0xffff0000u) | ((u32)lo & 0xfff8u) | tg;
        hp[r] = (u16)(uh >> 16);
      }
      st_dev16(pb + (nsl ? PAR : 0), (u32x4){atom[0], atom[1], atom[2], atom[3]});
      uint2 hvv;
      hvv.x = (u32)hp[0] | ((u32)hp[1] << 16);
      hvv.y = (u32)hp[2] | ((u32)hp[3] << 16);
      *(uint2*)hb = hvv;
    }
    hb += NBNN;

    // jx prefetch for next step (different address space; no poll hazard)
    if (s + 1 < NT) {
      ld_u16a(jxu, jp);
      jp += 2 * NBNN;
    }
  }
}

// ---------------- K3 (MFMA): out[b][t][o] = sum_n Hh[t][b][n]*Wout[o][n] + bout[o]
__global__ __launch_bounds__(256) void k_out(const u16* __restrict__ Hh,
                                             const u16* __restrict__ wouth,
                                             const float* __restrict__ bout,
                                             float* __restrict__ out) {
  const int t = blockIdx.x;
  const int tid = threadIdx.x;
  const int wv = tid >> 6, lane = tid & 63;
  __shared__ u16 Ah[NB][528];
  {
    const int b = tid >> 3, k0 = (tid & 7) * 64;
    const u16* hp = Hh + ((size_t)t * NB + b) * NN + k0;
#pragma unroll
    for (int j = 0; j < 8; ++j)
      *(uint4*)&Ah[b][k0 + 8 * j] = *(const uint4*)(hp + 8 * j);
  }
  __syncthreads();

  const int r15 = lane & 15, kg = lane >> 4;
  const int o = 16 * wv + r15;
  f32x4 acc[2] = {{0.f, 0.f, 0.f, 0.f}, {0.f, 0.f, 0.f, 0.f}};
#pragma unroll
  for (int kt = 0; kt < 16; ++kt) {
    const int ko = 32 * kt + 8 * kg;
    const bf16x8 b0 = *(const bf16x8*)(wouth + (size_t)o * NN + ko);
    const bf16x8 a0 = *(const bf16x8*)&Ah[r15][ko];
    const bf16x8 a1 = *(const bf16x8*)&Ah[16 + r15][ko];
    acc[0] = __builtin_amdgcn_mfma_f32_16x16x32_bf16(a0, b0, acc[0], 0, 0, 0);
    acc[1] = __builtin_amdgcn_mfma_f32_16x16x32_bf16(a1, b0, acc[1], 0, 0, 0);
  }
  const float bo = bout[o];
#pragma unroll
  for (int mt = 0; mt < 2; ++mt)
#pragma unroll
    for (int r = 0; r < 4; ++r) {
      const int b = 16 * mt + 4 * kg + r;
      out[((size_t)b * NT + t) * NOUT + o] = acc[mt][r] + bo;
    }
}

// ---------------- launch ----------------------------------------------------
// ws: [0, 65,536,000)             jx bf16 [NT][NB][NN]  (post-scan: wouth @ +0)
//     [65,536,000, 131,072,000)   Hh bf16 [NT][NB][NN]  (pre-scan: winh @ +0)
//     [131,072,000, 131,203,072)  Hex u32 [2][NB][NN]   (4B self-tagged atoms)
extern "C" void kernel_launch(void* const* d_in, const int* in_sizes, int n_in,
                              void* d_out, int out_size, void* d_ws, size_t ws_size,
                              hipStream_t stream) {
  (void)in_sizes; (void)n_in; (void)out_size;
  const float* x    = (const float*)d_in[0];
  const float* Wrec = (const float*)d_in[1];
  const float* brec = (const float*)d_in[2];
  const float* Win  = (const float*)d_in[3];
  const float* Wout = (const float*)d_in[4];
  const float* bout = (const float*)d_in[5];
  float* out = (float*)d_out;

  if (ws_size < 131203072ULL) return;  // visible failure beacon

  char* ws = (char*)d_ws;
  u16* jx    = (u16*)ws;
  u16* Hh    = (u16*)(ws + 65536000);
  u32* Hex   = (u32*)(ws + 131072000);
  u16* winh  = (u16*)(ws + 65536000);  // overlays Hh (dead until k_scan)
  u16* wouth = (u16*)ws;               // overlays jx (dead after k_scan)

  hipMemsetAsync(Hex, 0, 2 * PAR, stream);   // kill poison/cross-launch tag aliases
  k_prep_in<<<dim3((NN * NIN + 255) / 256), dim3(256), 0, stream>>>(Win, winh);
  k_in<<<dim3(NT), dim3(256), 0, stream>>>(x, winh, jx);
  k_scan<<<dim3(64), dim3(256), 0, stream>>>(Wrec, brec, jx, Hex, Hh);
  k_prep_out<<<dim3((NOUT * NN + 255) / 256), dim3(256), 0, stream>>>(Wout, wouth);
  k_out<<<dim3(NT), dim3(256), 0, stream>>>(Hh, wouth, bout, out);
}

// Round 13
// 3301.180 us; speedup vs baseline: 2.9882x; 1.1928x over previous
//
#include <hip/hip_runtime.h>
#include <hip/hip_bf16.h>
#include <cstdint>

// RateModel: h_{s+1} = tanh(W_rec h_s + b_rec + W_in x_s); out = W_out h + b_out
// B=32, Nt=2000 (sequential), N=512, N_in=128, N_out=64.
//
// k_scan R13 = R11 (proven: 3890us) + two individually-proven deltas:
//  - delta1 (timing-only): s_sleep 5 (~320cy) BEFORE the first poll issue, so
//    the first MALL sample lands after peers' publish-commit window ->
//    deterministic round-1 hit instead of a ~50% race (R11 lost a full RTT on
//    misses). Pure delay; cannot affect correctness.
//  - delta2 (R5-proven shape): own 64 rows self-staged via LDS ds_write in the
//    epilogue; own rows excluded from the tag wait (ok |= ownrow). Removes the
//    own-store-commit dependency from the critical path.
//  Poll discipline unchanged from R11: STRICTLY issue -> vmcnt(0) -> check,
//  consume immediately. NO in-flight asm-load registers across control flow
//  (R12 lesson: regalloc splits/spills in-flight load dests -> garbage).
//  Atom = 4B [hi16 | lo13 | tag3], tag = step&7, sc0 sc1 (MALL, any placement);
//  skew<=1 => stale tag differs by 2 mod 8 => never false-validates; Hex
//  memsetAsync(0) per launch. Deterministic, replay-safe.

#define NB   32
#define NT   2000
#define NIN  128
#define NN   512
#define NOUT 64
#define NBNN (NB * NN)
#define PAR  65536            // bytes per parity slot (u32[32][512])

typedef unsigned short u16;
typedef unsigned int   u32;
typedef unsigned long long u64;
typedef __bf16 bf16x8 __attribute__((ext_vector_type(8)));
typedef float  f32x4  __attribute__((ext_vector_type(4)));
typedef u32    u32x4  __attribute__((ext_vector_type(4)));

static __device__ __forceinline__ u16 f2bf(float f) {
  return __builtin_bit_cast(u16, (__bf16)f);   // RNE
}
static __device__ __forceinline__ float bf2f(u16 u) {
  return (float)__builtin_bit_cast(__bf16, u);
}
static __device__ __forceinline__ void split_hl(float f, u16& hi, u16& lo) {
  const u32 u = __float_as_uint(f);
  hi = (u16)(u >> 16);                                   // truncated bf16
  lo = f2bf(f - __uint_as_float(u & 0xffff0000u));       // residual
}
static __device__ __forceinline__ float fast_tanh(float x) {
  const float xc = fminf(fmaxf(x, -12.f), 12.f);
  const float t = __builtin_amdgcn_exp2f(xc * 2.8853900817779268f); // 2*log2(e)
  return (t - 1.f) * __builtin_amdgcn_rcpf(t + 1.f);
}

// device-scope (MALL) 16B ops; vmcnt-only, invisible to compiler's wait model
static __device__ __forceinline__ u32x4 ld_dev16(const void* p) {
  u32x4 r;
  asm volatile("global_load_dwordx4 %0, %1, off sc0 sc1" : "=v"(r) : "v"(p) : "memory");
  return r;
}
static __device__ __forceinline__ void st_dev16(void* p, u32x4 v) {
  asm volatile("global_store_dwordx4 %0, %1, off sc0 sc1" :: "v"(p), "v"(v) : "memory");
}
static __device__ __forceinline__ void ld_u16a(u32& d, const void* p) {
  asm volatile("global_load_ushort %0, %1, off" : "=v"(d) : "v"(p) : "memory");
}
static __device__ __forceinline__ bool tags8(u32x4 a, u32x4 b, u32 want) {
  return ((a.x & 7u) == want) & ((a.y & 7u) == want) &
         ((a.z & 7u) == want) & ((a.w & 7u) == want) &
         ((b.x & 7u) == want) & ((b.y & 7u) == want) &
         ((b.z & 7u) == want) & ((b.w & 7u) == want);
}

// ---------------- prep: bf16 weight tables --------------------------------
__global__ __launch_bounds__(256) void k_prep_in(const float* __restrict__ Win,
                                                 u16* __restrict__ winh) {
  const int e = blockIdx.x * 256 + threadIdx.x;
  if (e < NN * NIN) winh[e] = f2bf(Win[e]);
}
__global__ __launch_bounds__(256) void k_prep_out(const float* __restrict__ Wout,
                                                  u16* __restrict__ wouth) {
  const int e = blockIdx.x * 256 + threadIdx.x;
  if (e < NOUT * NN) wouth[e] = f2bf(Wout[e]);
}

// ---------------- K1 (MFMA): jx[t][b][n] = sum_k x[b][t][k] * Win[n][k] ----
__global__ __launch_bounds__(256) void k_in(const float* __restrict__ x,
                                            const u16* __restrict__ winh,
                                            u16* __restrict__ jx) {
  const int t = blockIdx.x;
  const int tid = threadIdx.x;
  const int wv = tid >> 6, lane = tid & 63;
  __shared__ u16 Xh[NB][136];
  __shared__ u16 Xl[NB][136];
  {
    const int b = tid >> 3, k0 = (tid & 7) * 16;
    const float* xp = x + ((size_t)b * NT + t) * NIN + k0;
    u16 hb[16], lb[16];
#pragma unroll
    for (int j = 0; j < 16; ++j) split_hl(xp[j], hb[j], lb[j]);
    *(uint4*)&Xh[b][k0]     = *(uint4*)&hb[0];
    *(uint4*)&Xh[b][k0 + 8] = *(uint4*)&hb[8];
    *(uint4*)&Xl[b][k0]     = *(uint4*)&lb[0];
    *(uint4*)&Xl[b][k0 + 8] = *(uint4*)&lb[8];
  }
  __syncthreads();

  const int r15 = lane & 15, kg = lane >> 4;
  const int n0 = 128 * wv;
  f32x4 acc[2][8];
#pragma unroll
  for (int mt = 0; mt < 2; ++mt)
#pragma unroll
    for (int nt = 0; nt < 8; ++nt) acc[mt][nt] = (f32x4){0.f, 0.f, 0.f, 0.f};

#pragma unroll
  for (int kt = 0; kt < 4; ++kt) {
    const int ko = 32 * kt + 8 * kg;
    const bf16x8 ah0 = *(const bf16x8*)&Xh[r15][ko];
    const bf16x8 ah1 = *(const bf16x8*)&Xh[16 + r15][ko];
    const bf16x8 al0 = *(const bf16x8*)&Xl[r15][ko];
    const bf16x8 al1 = *(const bf16x8*)&Xl[16 + r15][ko];
#pragma unroll
    for (int nt = 0; nt < 8; ++nt) {
      const int n = n0 + 16 * nt + r15;
      const bf16x8 bh = *(const bf16x8*)(winh + (size_t)n * NIN + ko);
      acc[0][nt] = __builtin_amdgcn_mfma_f32_16x16x32_bf16(ah0, bh, acc[0][nt], 0, 0, 0);
      acc[1][nt] = __builtin_amdgcn_mfma_f32_16x16x32_bf16(ah1, bh, acc[1][nt], 0, 0, 0);
      acc[0][nt] = __builtin_amdgcn_mfma_f32_16x16x32_bf16(al0, bh, acc[0][nt], 0, 0, 0);
      acc[1][nt] = __builtin_amdgcn_mfma_f32_16x16x32_bf16(al1, bh, acc[1][nt], 0, 0, 0);
    }
  }
#pragma unroll
  for (int mt = 0; mt < 2; ++mt)
#pragma unroll
    for (int nt = 0; nt < 8; ++nt) {
      const int n = n0 + 16 * nt + r15;
#pragma unroll
      for (int r = 0; r < 4; ++r) {
        const int b = 16 * mt + 4 * kg + r;
        jx[((size_t)t * NB + b) * NN + n] = f2bf(acc[mt][nt][r]);
      }
    }
}

// ---------------- K2: sequential scan --------------------------------------
__global__ __launch_bounds__(256) void k_scan(const float* __restrict__ Wrec,
                                              const float* __restrict__ brec,
                                              const u16* __restrict__ jx,
                                              u32* Hex,             // [2][NB][NN] 4B atoms
                                              u16* __restrict__ Hh) // [NT][NB][NN]
{
  const int wg = blockIdx.x;
  const int g = wg & 7, i = wg >> 3;
  const int tid = threadIdx.x;
  const int wv = tid >> 6, lane = tid & 63;

  // stride 528 u16 = 264 dw == 8 (mod 32): B-frag ds_read_b128 2-way -> free (m136)
  __shared__ u16 SHhi[2][4][528];
  __shared__ u16 SHlo[2][4][528];
  __shared__ float Pj[2][4][64];

  const int r15 = lane & 15, kg = lane >> 4;
  const int t64 = tid & 63;
  const float brv = brec[64 * i + t64];

  // resident A-frags: row = lane&15, k = 8*kg + j (contig-8)
  const int arow = 64 * i + 16 * wv + r15;
  bf16x8 afrag[16];
#pragma unroll
  for (int kt = 0; kt < 16; ++kt) {
    const float* wp = Wrec + (size_t)arow * NN + 32 * kt + 8 * kg;
    bf16x8 a;
#pragma unroll
    for (int j = 0; j < 8; ++j) a[j] = (__bf16)wp[j];
    afrag[kt] = a;
  }

  const int sc = wv;                 // staged chain (== wave)
  const int cc = r15;                // D col = chain (valid < 4)
  const int rb = 16 * wv + 4 * kg;   // D row base within WG slice
  const int gch = 4 * g + cc;
  const int ro = 64 * i + rb;        // global rows ro..ro+3 (ro%4==0)
  const bool ownrow = ((t64 >> 3) == i);  // polled rows are own WG's rows

  char* HexB_ = (char*)Hex;
  // consumer: rows 8*t64..+7 of chain sc -> 32B contiguous
  const char* cb = HexB_ + ((size_t)(4 * g + sc) * NN + 8 * t64) * 4;
  // producer: rows ro..ro+3 of chain gch -> one 16B line
  char* pb = HexB_ + ((size_t)gch * NN + ro) * 4;

  const char* jp = (const char*)jx + ((size_t)(NB + 4 * g + sc) * NN + 64 * i + t64) * 2;
  u16* hb = Hh + (size_t)gch * NN + ro;

  const float jxv0 = bf2f(jx[(size_t)(4 * g + sc) * NN + 64 * i + t64]);
  u32 jxu = 0;

  for (int s = 0; s < NT; ++s) {
    const int slot = s & 1;
    if (s > 0) {
      // delta1: delay first poll so its MALL sample lands after peers'
      // publish-commit window -> round-1 hit (pure timing, no protocol change)
      asm volatile("s_sleep 5" :::);
      const char* cbs = cb + (slot ? PAR : 0);
      const u32 want = (u32)s & 7u;
      u32x4 A0 = ld_dev16(cbs);
      u32x4 A1 = ld_dev16(cbs + 16);
      asm volatile("s_waitcnt vmcnt(0)" ::: "memory");  // also drains jx + acks
      __builtin_amdgcn_sched_barrier(0);
      bool ok = ownrow | tags8(A0, A1, want);
      int guard = 1 << 16;                               // anti-hang only
      while (!__all(ok) && --guard) {
        A0 = ld_dev16(cbs);
        A1 = ld_dev16(cbs + 16);
        asm volatile("s_waitcnt vmcnt(0)" ::: "memory");
        __builtin_amdgcn_sched_barrier(0);
        ok = ownrow | tags8(A0, A1, want);
      }
      if (!ownrow) {
        // unpack: atom = [hi16 | lo13 | tag3]; rows ascend A0.x..A1.w
        const u32x4 hw = {(A0.x >> 16) | (A0.y & 0xffff0000u),
                          (A0.z >> 16) | (A0.w & 0xffff0000u),
                          (A1.x >> 16) | (A1.y & 0xffff0000u),
                          (A1.z >> 16) | (A1.w & 0xffff0000u)};
        const u32x4 lw = {(A0.x & 0xfff8u) | ((A0.y & 0xfff8u) << 16),
                          (A0.z & 0xfff8u) | ((A0.w & 0xfff8u) << 16),
                          (A1.x & 0xfff8u) | ((A1.y & 0xfff8u) << 16),
                          (A1.z & 0xfff8u) | ((A1.w & 0xfff8u) << 16)};
        *(u32x4*)&SHhi[slot][sc][8 * t64] = hw;
        *(u32x4*)&SHlo[slot][sc][8 * t64] = lw;
      }
      Pj[slot][sc][t64] = __uint_as_float(jxu << 16) + brv;
    } else {
      Pj[0][sc][t64] = jxv0 + brv;
    }

    // single barrier per step: drains only LDS writes (globals are vmcnt-only)
    asm volatile("s_waitcnt lgkmcnt(0)" ::: "memory");
    __builtin_amdgcn_s_barrier();
    __builtin_amdgcn_sched_barrier(0);

    // 4 independent MFMA chains: hi/lo x K-halves (breaks dependent latency)
    f32x4 ah0 = {0.f, 0.f, 0.f, 0.f}, ah1 = {0.f, 0.f, 0.f, 0.f};
    f32x4 al0 = {0.f, 0.f, 0.f, 0.f}, al1 = {0.f, 0.f, 0.f, 0.f};
    if (s > 0) {
      const int c4 = cc & 3;
#pragma unroll
      for (int kt = 0; kt < 8; ++kt) {
        const int ko  = 32 * kt + 8 * kg;
        const int ko2 = 32 * (kt + 8) + 8 * kg;
        const bf16x8 bh0 = *(const bf16x8*)&SHhi[slot][c4][ko];
        const bf16x8 bh1 = *(const bf16x8*)&SHhi[slot][c4][ko2];
        const bf16x8 bl0 = *(const bf16x8*)&SHlo[slot][c4][ko];
        const bf16x8 bl1 = *(const bf16x8*)&SHlo[slot][c4][ko2];
        ah0 = __builtin_amdgcn_mfma_f32_16x16x32_bf16(afrag[kt],     bh0, ah0, 0, 0, 0);
        ah1 = __builtin_amdgcn_mfma_f32_16x16x32_bf16(afrag[kt + 8], bh1, ah1, 0, 0, 0);
        al0 = __builtin_amdgcn_mfma_f32_16x16x32_bf16(afrag[kt],     bl0, al0, 0, 0, 0);
        al1 = __builtin_amdgcn_mfma_f32_16x16x32_bf16(afrag[kt + 8], bl1, al1, 0, 0, 0);
      }
    }
    const f32x4 acc = (ah0 + ah1) + (al0 + al1);

    // epilogue: publish FIRST, self-stage own rows (delta2, R5-proven shape),
    // then Hh, then jx prefetch
    const int nsl = (s + 1) & 1;
    if (cc < 4) {
      const u32 tg = (u32)(s + 1) & 7u;
      u32 atom[4];
      u16 hp[4], lp[4];
#pragma unroll
      for (int r = 0; r < 4; ++r) {
        const float pre = acc[r] + Pj[slot][cc][rb + r];
        const float h = fast_tanh(pre);
        const u32 uh = __float_as_uint(h);
        lp[r] = (u16)(f2bf(h - __uint_as_float(uh & 0xffff0000u)) & 0xfff8u);
        hp[r] = (u16)(uh >> 16);
        atom[r] = (uh & 0xffff0000u) | (u32)lp[r] | tg;
      }
      st_dev16(pb + (nsl ? PAR : 0), (u32x4){atom[0], atom[1], atom[2], atom[3]});
      // self-stage own rows into next-slot LDS (never polled; same lo13 values)
      uint2 hw2, lw2;
      hw2.x = (u32)hp[0] | ((u32)hp[1] << 16);
      hw2.y = (u32)hp[2] | ((u32)hp[3] << 16);
      lw2.x = (u32)lp[0] | ((u32)lp[1] << 16);
      lw2.y = (u32)lp[2] | ((u32)lp[3] << 16);
      *(uint2*)&SHhi[nsl][cc][ro] = hw2;
      *(uint2*)&SHlo[nsl][cc][ro] = lw2;
      *(uint2*)hb = hw2;
    }
    hb += NBNN;

    // jx prefetch for next step (different address; no poll hazard)
    if (s + 1 < NT) {
      ld_u16a(jxu, jp);
      jp += 2 * NBNN;
    }
  }
}

// ---------------- K3 (MFMA): out[b][t][o] = sum_n Hh[t][b][n]*Wout[o][n] + bout[o]
__global__ __launch_bounds__(256) void k_out(const u16* __restrict__ Hh,
                                             const u16* __restrict__ wouth,
                                             const float* __restrict__ bout,
                                             float* __restrict__ out) {
  const int t = blockIdx.x;
  const int tid = threadIdx.x;
  const int wv = tid >> 6, lane = tid & 63;
  __shared__ u16 Ah[NB][528];
  {
    const int b = tid >> 3, k0 = (tid & 7) * 64;
    const u16* hp = Hh + ((size_t)t * NB + b) * NN + k0;
#pragma unroll
    for (int j = 0; j < 8; ++j)
      *(uint4*)&Ah[b][k0 + 8 * j] = *(const uint4*)(hp + 8 * j);
  }
  __syncthreads();

  const int r15 = lane & 15, kg = lane >> 4;
  const int o = 16 * wv + r15;
  f32x4 acc[2] = {{0.f, 0.f, 0.f, 0.f}, {0.f, 0.f, 0.f, 0.f}};
#pragma unroll
  for (int kt = 0; kt < 16; ++kt) {
    const int ko = 32 * kt + 8 * kg;
    const bf16x8 b0 = *(const bf16x8*)(wouth + (size_t)o * NN + ko);
    const bf16x8 a0 = *(const bf16x8*)&Ah[r15][ko];
    const bf16x8 a1 = *(const bf16x8*)&Ah[16 + r15][ko];
    acc[0] = __builtin_amdgcn_mfma_f32_16x16x32_bf16(a0, b0, acc[0], 0, 0, 0);
    acc[1] = __builtin_amdgcn_mfma_f32_16x16x32_bf16(a1, b0, acc[1], 0, 0, 0);
  }
  const float bo = bout[o];
#pragma unroll
  for (int mt = 0; mt < 2; ++mt)
#pragma unroll
    for (int r = 0; r < 4; ++r) {
      const int b = 16 * mt + 4 * kg + r;
      out[((size_t)b * NT + t) * NOUT + o] = acc[mt][r] + bo;
    }
}

// ---------------- launch ----------------------------------------------------
// ws: [0, 65,536,000)             jx bf16 [NT][NB][NN]  (post-scan: wouth @ +0)
//     [65,536,000, 131,072,000)   Hh bf16 [NT][NB][NN]  (pre-scan: winh @ +0)
//     [131,072,000, 131,203,072)  Hex u32 [2][NB][NN]   (4B self-tagged atoms)
extern "C" void kernel_launch(void* const* d_in, const int* in_sizes, int n_in,
                              void* d_out, int out_size, void* d_ws, size_t ws_size,
                              hipStream_t stream) {
  (void)in_sizes; (void)n_in; (void)out_size;
  const float* x    = (const float*)d_in[0];
  const float* Wrec = (const float*)d_in[1];
  const float* brec = (const float*)d_in[2];
  const float* Win  = (const float*)d_in[3];
  const float* Wout = (const float*)d_in[4];
  const float* bout = (const float*)d_in[5];
  float* out = (float*)d_out;

  if (ws_size < 131203072ULL) return;  // visible failure beacon

  char* ws = (char*)d_ws;
  u16* jx    = (u16*)ws;
  u16* Hh    = (u16*)(ws + 65536000);
  u32* Hex   = (u32*)(ws + 131072000);
  u16* winh  = (u16*)(ws + 65536000);  // overlays Hh (dead until k_scan)
  u16* wouth = (u16*)ws;               // overlays jx (dead after k_scan)

  hipMemsetAsync(Hex, 0, 2 * PAR, stream);   // kill poison/cross-launch tag aliases
  k_prep_in<<<dim3((NN * NIN + 255) / 256), dim3(256), 0, stream>>>(Win, winh);
  k_in<<<dim3(NT), dim3(256), 0, stream>>>(x, winh, jx);
  k_scan<<<dim3(64), dim3(256), 0, stream>>>(Wrec, brec, jx, Hex, Hh);
  k_prep_out<<<dim3((NOUT * NN + 255) / 256), dim3(256), 0, stream>>>(Wout, wouth);
  k_out<<<dim3(NT), dim3(256), 0, stream>>>(Hh, wouth, bout, out);
}